// Round 11
// baseline (234.274 us; speedup 1.0000x reference)
//
#include <hip/hip_runtime.h>
#include <hip/hip_fp16.h>
#include <math.h>

// TreeBackbone — round 11: conv moved to MFMA (v_mfma_f32_16x16x32_bf16).
//  Per (g,oy,half): D[ox(16)][f(16)] = X-window frags x W frags, K-slots
//  (q=ky 0..3, j=kx 0..7; kx>4 weight=0); ky=4 via 2nd frag (q==0 rows only).
//  Slot-label-robust: A and B built with the SAME (q,j)->tap map, so any HW
//  k-labeling contracts correctly. Assumes arg0 = M-side, C/D col=lane&15,
//  row=4*(lane>>4)+reg (m89-verified).
//  A-frag = ONE ds_read_b128 from R[g][row][OX][8] bf16 sliding windows
//  (pre-shifted -> aligned; row block padded to 30 OX -> bank shifts 0/24/16/8).
//  Pool: in-lane (ox pairs adjacent C regs, oy pairs two accs) + sigmoid,
//  f16 direct to global chunks. Tree/prep_tw = round 10 verbatim.

#define NTW   (21 * 15 * 16 * 32)
#define TWBYTES (NTW * 2)
#define WFRAG_HALFS (3 * 2 * 64 * 8)     // [g][frag][lane][8] bf16
#define WFRAG_BYTES (WFRAG_HALFS * 2)
#define POOL_HALF 10080
#define POOL_BYTES (POOL_HALF * 2)

typedef __fp16 h2v __attribute__((ext_vector_type(2)));
typedef short short8v __attribute__((ext_vector_type(8)));
typedef float float4v __attribute__((ext_vector_type(4)));
union HU { unsigned u; h2v v; };
union FRAG { uint4 u; short8v s; };

#if defined(__has_builtin)
#if __has_builtin(__builtin_amdgcn_fdot2)
#define HAVE_FDOT2 1
#endif
#endif

__device__ __forceinline__ float sigmoidf_(float v) {
    return 1.0f / (1.0f + __expf(-v));
}
__device__ __forceinline__ h2v as_h2(unsigned x) { HU t; t.u = x; return t.v; }
__device__ __forceinline__ ushort f2bf(float v) {
    unsigned u = __float_as_uint(v);
    u += 0x7fffu + ((u >> 16) & 1u);
    return (ushort)(u >> 16);
}
__device__ __forceinline__ unsigned pack_bf2(float a, float b) {   // {lo=a, hi=b}
    unsigned ua = __float_as_uint(a); ua += 0x7fffu + ((ua >> 16) & 1u);
    unsigned ub = __float_as_uint(b); ub += 0x7fffu + ((ub >> 16) & 1u);
    return (ua >> 16) | (ub & 0xffff0000u);
}

// ---- prep 1: tree weights fp32 -> f16 [gh][f][o][32] (round 10 verbatim) ----
__global__ __launch_bounds__(256) void prep_tw(
    const float* __restrict__ tw, __half* __restrict__ tw2)
{
    int i = blockIdx.x * 256 + threadIdx.x;
    if (i >= NTW) return;
    const int e   = i & 31;
    const int o   = (i >> 5) & 15;
    const int fgh = i >> 9;
    const int f   = fgh % 15, gh = fgh / 15;
    const int g   = gh / 7,  h  = gh % 7;
    float v = 0.f;
    if (e < 28) {
        const int i2 = e / 14, rem = e % 14, w = rem >> 1, j = rem & 1;
        v = tw[o * 8820 + f * 588 + g * 196 + h * 28 + w * 4 + i2 * 2 + j];
    }
    tw2[i] = __float2half(v);
}

// ---- prep 2: conv weight MFMA fragments, bf16 [g][frag][lane][8] ----
//  slot (q=lane>>4, j): frag0: w[ky=q][kx=j] (j<5 else 0); frag1 (ky=4):
//  q==0 && j<5 -> w[4][j] else 0. n=f=lane&15 (f==15 -> 0).
__global__ __launch_bounds__(256) void prep_wf(
    const float* __restrict__ cw, ushort* __restrict__ wfrag)
{
    int i = blockIdx.x * 256 + threadIdx.x;
    if (i >= 384) return;
    const int g  = i >> 7, rem = i & 127, fr = rem >> 6, l = rem & 63;
    const int f  = l & 15, q = l >> 4;
    ushort o[8];
    #pragma unroll
    for (int j = 0; j < 8; ++j) {
        float v = 0.f;
        if (f < 15 && j < 5) {
            if (fr == 0)           v = cw[(g * 15 + f) * 25 + q * 5 + j];
            else if (q == 0)       v = cw[(g * 15 + f) * 25 + 20 + j];
        }
        o[j] = f2bf(v);
    }
    ushort* d = wfrag + ((g * 2 + fr) * 64 + l) * 8;
    *(uint4*)d = make_uint4(
        (unsigned)o[0] | ((unsigned)o[1] << 16),
        (unsigned)o[2] | ((unsigned)o[3] << 16),
        (unsigned)o[4] | ((unsigned)o[5] << 16),
        (unsigned)o[6] | ((unsigned)o[7] << 16));
}

// ---- kernel A: MFMA conv + pool + sigmoid -> f16 pool chunks ----
__global__ __launch_bounds__(256) void conv_pool_mfma(
    const float* __restrict__ x,      // (B,3,32,32)
    const float* __restrict__ cb,     // (45,)
    const ushort* __restrict__ wfrag, // [g][frag][lane][8] bf16
    __half* __restrict__ pool16,      // (B, 10080) f16
    int B)
{
    __shared__ __align__(16) ushort s_R[3 * 32 * 30 * 8];  // 46080 B windows
    __shared__ float  s_cb[45];
    __shared__ __align__(16) ushort s_zero[8];

    const int b = blockIdx.x;
    if (b >= B) return;
    const int t = threadIdx.x;

    // ---- build sliding windows: thread t<96 owns (g = t/32, row = t%32) ----
    if (t < 96) {
        const int g = t / 32, row = t % 32;
        const float4* xr = (const float4*)(x + (size_t)b * 3072 + t * 32);
        unsigned u[18], s[18];
        #pragma unroll
        for (int k = 0; k < 8; ++k) {
            const float4 v = xr[k];
            u[2 * k]     = pack_bf2(v.x, v.y);
            u[2 * k + 1] = pack_bf2(v.z, v.w);
        }
        u[16] = 0u; u[17] = 0u;
        #pragma unroll
        for (int k = 0; k < 17; ++k) s[k] = (u[k] >> 16) | (u[k + 1] << 16);
        s[17] = 0u;
        ushort* rb = &s_R[((g * 32 + row) * 30) * 8];
        #pragma unroll
        for (int OX = 0; OX < 30; ++OX) {
            uint4 qd;
            if ((OX & 1) == 0) {
                const int hh = OX >> 1;
                qd = make_uint4(u[hh], u[hh + 1], u[hh + 2], u[hh + 3]);
            } else {
                const int hh = (OX - 1) >> 1;
                qd = make_uint4(s[hh], s[hh + 1], s[hh + 2], s[hh + 3]);
            }
            *(uint4*)&rb[OX * 8] = qd;
        }
    }
    if (t < 45) s_cb[t] = cb[t];
    if (t == 96) *(uint4*)&s_zero[0] = make_uint4(0u, 0u, 0u, 0u);

    // per-lane weight fragments (persist in regs)
    const int lane = t & 63, wv = t >> 6;
    const int q = lane >> 4, oxl = lane & 15;
    FRAG w1[3], w2[3];
    {
        const uint4* wf4 = (const uint4*)wfrag;
        #pragma unroll
        for (int g2 = 0; g2 < 3; ++g2) {
            w1[g2].u = wf4[(g2 * 2 + 0) * 64 + lane];
            w2[g2].u = wf4[(g2 * 2 + 1) * 64 + lane];
        }
    }
    __syncthreads();

    const int LC = q * 240 + oxl * 8;          // lane-constant (halfs)
    const float4v z4 = {0.f, 0.f, 0.f, 0.f};

    #pragma unroll 1
    for (int i = 0; i < 21; ++i) {
        const int tp = wv * 21 + i;            // 84 tile-pairs, wave-chunked
        const int g = tp / 28, r = tp - g * 28, py = r >> 1, half = r & 1;
        const int rowbase = ((g * 32 + 2 * py) * 30) * 8;
        const int off1 = rowbase + LC + half * 112;

        FRAG a10, a11, a20, a21;
        a10.u = *(const uint4*)&s_R[off1];          // rows 2py+q
        a11.u = *(const uint4*)&s_R[off1 + 240];    // rows 2py+1+q
        const ushort* p20 = (q == 0)
            ? &s_R[rowbase + 4 * 240 + oxl * 8 + half * 112] : &s_zero[0];
        const ushort* p21 = (q == 0)
            ? &s_R[rowbase + 5 * 240 + oxl * 8 + half * 112] : &s_zero[0];
        a20.u = *(const uint4*)p20;
        a21.u = *(const uint4*)p21;

        float4v acc0 = __builtin_amdgcn_mfma_f32_16x16x32_bf16(a20.s, w2[g].s, z4, 0, 0, 0);
        acc0 = __builtin_amdgcn_mfma_f32_16x16x32_bf16(a10.s, w1[g].s, acc0, 0, 0, 0);
        float4v acc1 = __builtin_amdgcn_mfma_f32_16x16x32_bf16(a21.s, w2[g].s, z4, 0, 0, 0);
        acc1 = __builtin_amdgcn_mfma_f32_16x16x32_bf16(a11.s, w1[g].s, acc1, 0, 0, 0);

        // epilogue: this lane is output (f = lane&15, ox quad = lane>>4)
        const int f = oxl;
        if (f < 15) {
            const float bias = s_cb[g * 15 + f];
            const float p0 = fmaxf(fmaxf(acc0[0], acc0[1]), fmaxf(acc1[0], acc1[1]));
            const float p1 = fmaxf(fmaxf(acc0[2], acc0[3]), fmaxf(acc1[2], acc1[3]));
            __half* chunk = pool16 + (size_t)b * POOL_HALF
                          + (size_t)((g * 15 + f) * 7 + (py >> 1)) * 32;
            const int e0 = (py & 1) * 14 + half * 7 + 2 * q;
            chunk[e0] = __float2half_rn(sigmoidf_(p0 + bias));
            if (q < 3)
                chunk[e0 + 1] = __float2half_rn(sigmoidf_(p1 + bias));
            if (half == 0 && (py & 1) == 0 && q == 3)       // zero pad e28..31 once
                *(uint2*)((char*)chunk + 56) = make_uint2(0u, 0u);
        }
    }
}

// ---- kernel B: tree, 256 thr = 64 images x 4 f-groups, dot2 (r10 verbatim) ----
__global__ __launch_bounds__(256) void tree_kernel(
    const __half* __restrict__ pool16,
    const __half* __restrict__ tw2,
    const float* __restrict__ tb,
    float* __restrict__ out,
    int B, int nblk)
{
    __shared__ float s_red[256 * 17];

    const int cpx = nblk / 8;
    const int sid = (blockIdx.x % 8) * cpx + blockIdx.x / 8;
    const int gh = sid % 21, tile = sid / 21;
    const int g = gh / 7, h = gh % 7;

    const int t  = threadIdx.x;
    const int bl = t & 63, fg = t >> 6;
    const int b  = tile * 64 + bl;
    if (b >= B) return;

    const int f0 = fg * 4;
    const int nf = (fg < 3) ? 4 : 3;

    float acc[16];
    #pragma unroll
    for (int o = 0; o < 16; ++o) acc[o] = 0.f;

    #pragma unroll 1
    for (int fi = 0; fi < nf; ++fi) {
        const int f = f0 + fi;
        const uint4* pc = (const uint4*)(pool16 + (size_t)b * POOL_HALF
                                         + ((g * 15 + f) * 7 + h) * 32);
        const uint4* wc = (const uint4*)(tw2 + (size_t)((gh * 15 + f) * 16) * 32);
        uint4 pu[4];
        #pragma unroll
        for (int k = 0; k < 4; ++k) pu[k] = pc[k];
        #pragma unroll
        for (int o = 0; o < 16; ++o) {
            #pragma unroll
            for (int k = 0; k < 4; ++k) {
                const uint4 wu = wc[o * 4 + k];
#ifdef HAVE_FDOT2
                acc[o] = __builtin_amdgcn_fdot2(as_h2(pu[k].x), as_h2(wu.x), acc[o], false);
                acc[o] = __builtin_amdgcn_fdot2(as_h2(pu[k].y), as_h2(wu.y), acc[o], false);
                acc[o] = __builtin_amdgcn_fdot2(as_h2(pu[k].z), as_h2(wu.z), acc[o], false);
                acc[o] = __builtin_amdgcn_fdot2(as_h2(pu[k].w), as_h2(wu.w), acc[o], false);
#else
                const unsigned pw[4] = {pu[k].x, pu[k].y, pu[k].z, pu[k].w};
                const unsigned ww[4] = {wu.x, wu.y, wu.z, wu.w};
                #pragma unroll
                for (int qq = 0; qq < 4; ++qq) {
                    acc[o] += __half2float(__ushort_as_half((ushort)(pw[qq] & 0xffff)))
                            * __half2float(__ushort_as_half((ushort)(ww[qq] & 0xffff)));
                    acc[o] += __half2float(__ushort_as_half((ushort)(pw[qq] >> 16)))
                            * __half2float(__ushort_as_half((ushort)(ww[qq] >> 16)));
                }
#endif
            }
        }
    }

    #pragma unroll
    for (int o = 0; o < 16; ++o) s_red[t * 17 + o] = acc[o];
    __syncthreads();

    const int og = t >> 6;
    #pragma unroll
    for (int m = 0; m < 4; ++m) {
        const int o = og * 4 + m;
        float a = s_red[(0 * 64 + bl) * 17 + o] + s_red[(1 * 64 + bl) * 17 + o]
                + s_red[(2 * 64 + bl) * 17 + o] + s_red[(3 * 64 + bl) * 17 + o];
        const int idx = o * 21 + gh;
        out[(size_t)b * 336 + idx] = sigmoidf_(a + tb[idx]);
    }
}

// ---- fallback: round-2 fused kernel verbatim (fp32, known-good) ----
__global__ __launch_bounds__(256) void tree_backbone_legacy(
    const float* __restrict__ x, const float* __restrict__ cw,
    const float* __restrict__ cb, const float* __restrict__ tw,
    const float* __restrict__ tb, float* __restrict__ out, int B)
{
    __shared__ float s_x[3 * 32 * 36];
    __shared__ float s_cwl[45 * 25];
    __shared__ float s_cb[45];
    __shared__ float s_pool[45][197];

    const int b = blockIdx.x;
    if (b >= B) return;
    const int t = threadIdx.x;

    const float4* xs = (const float4*)(x + (size_t)b * 3072);
    for (int i = t; i < 768; i += 256) {
        const float4 v = xs[i];
        const int g = i >> 8, rem = i & 255, r = rem >> 3, qq = rem & 7;
        const int p = ((r & 1) << 4) + (r >> 1);
        *(float4*)&s_x[(g * 32 + p) * 36 + qq * 4] = v;
    }
    for (int i = t; i < 1125; i += 256) s_cwl[i] = cw[i];
    if (t < 45) s_cb[t] = cb[t];
    __syncthreads();

    for (int task = t; task < 1260; task += 256) {
        const int h  = (task >= 630) ? 1 : 0;
        const int tt = task - 630 * h;
        const int c  = tt / 14;
        const int py = tt - c * 14;
        const int g  = c / 15;
        float aA[14], aB[14];
        #pragma unroll
        for (int d = 0; d < 14; ++d) { aA[d] = 0.f; aB[d] = 0.f; }
        #pragma unroll
        for (int dr = 0; dr < 6; ++dr) {
            const float* rp = s_x + (g * 32 + ((dr & 1) << 4) + py + (dr >> 1)) * 36 + 12 * h;
            float f[20];
            #pragma unroll
            for (int k = 0; k < 5; ++k)
                *(float4*)&f[4 * k] = *(const float4*)&rp[4 * k];
            if (dr <= 4)
                #pragma unroll
                for (int kx = 0; kx < 5; ++kx) {
                    const float w = s_cwl[c * 25 + dr * 5 + kx];
                    #pragma unroll
                    for (int d = 0; d < 14; ++d) aA[d] += f[d + kx + 2 * h] * w;
                }
            if (dr >= 1)
                #pragma unroll
                for (int kx = 0; kx < 5; ++kx) {
                    const float w = s_cwl[c * 25 + (dr - 1) * 5 + kx];
                    #pragma unroll
                    for (int d = 0; d < 14; ++d) aB[d] += f[d + kx + 2 * h] * w;
                }
        }
        float* dst = &s_pool[c][py * 14 + 7 * h];
        #pragma unroll
        for (int p = 0; p < 7; ++p) {
            float m = fmaxf(fmaxf(aA[2 * p], aA[2 * p + 1]),
                            fmaxf(aB[2 * p], aB[2 * p + 1]));
            dst[p] = sigmoidf_(m + s_cb[c]);
        }
    }
    __syncthreads();

    for (int idx = t; idx < 336; idx += 256) {
        const int o  = idx / 21;
        const int r2 = idx - o * 21;
        const int g  = r2 / 7;
        const int hh = r2 - g * 7;
        const float* wp = tw + o * 8820 + g * 196 + hh * 28;
        float acc = 0.0f;
        #pragma unroll 1
        for (int f = 0; f < 15; ++f) {
            const float4* wf = (const float4*)(wp + f * 588);
            const float* p0 = &s_pool[g * 15 + f][(2 * hh) * 14];
            const float* p1 = p0 + 14;
            #pragma unroll
            for (int w = 0; w < 7; ++w) {
                const float4 qv = wf[w];
                acc += p0[2 * w] * qv.x + p0[2 * w + 1] * qv.y
                     + p1[2 * w] * qv.z + p1[2 * w + 1] * qv.w;
            }
        }
        out[(size_t)b * 336 + idx] = sigmoidf_(acc + tb[idx]);
    }
}

extern "C" void kernel_launch(void* const* d_in, const int* in_sizes, int n_in,
                              void* d_out, int out_size, void* d_ws, size_t ws_size,
                              hipStream_t stream) {
    const float* x  = (const float*)d_in[0];
    const float* cw = (const float*)d_in[1];
    const float* cb = (const float*)d_in[2];
    const float* tw = (const float*)d_in[3];
    const float* tb = (const float*)d_in[4];
    float* out = (float*)d_out;

    const int B = in_sizes[0] / 3072;   // 4096
    const size_t need = (size_t)TWBYTES + (size_t)WFRAG_BYTES + (size_t)B * POOL_BYTES;
    if (ws_size >= need) {
        __half* tw2    = (__half*)d_ws;
        ushort* wfrag  = (ushort*)((char*)d_ws + TWBYTES);
        __half* pool16 = (__half*)((char*)d_ws + TWBYTES + WFRAG_BYTES);
        const int nblk = (B / 64) * 21;
        prep_tw<<<(NTW + 255) / 256, 256, 0, stream>>>(tw, tw2);
        prep_wf<<<2, 256, 0, stream>>>(cw, wfrag);
        conv_pool_mfma<<<B, 256, 0, stream>>>(x, cb, wfrag, pool16, B);
        tree_kernel<<<nblk, 256, 0, stream>>>(pool16, tw2, tb, out, B, nblk);
    } else {
        tree_backbone_legacy<<<B, 256, 0, stream>>>(x, cw, cb, tw, tb, out, B);
    }
}

// Round 12
// 177.765 us; speedup vs baseline: 1.3179x; 1.3179x over previous
//
#include <hip/hip_runtime.h>
#include <hip/hip_fp16.h>
#include <math.h>

// TreeBackbone — round 12 = round 11 MFMA conv with the store path fixed.
//  r11 failure mode (measured): scattered per-lane 2B global stores -> 207MB
//  WRITE (2.5x amp) + RMW backpressure. Fix: sigma-permuted chunk layout
//  e' = parity*16 + half*8 + px (slot7 pad) so each lane writes ONE packed
//  u32 to an LDS pool (stride 40 halfs, 2-way banks), then coalesced uint4
//  flush. prep_tw uses the same sigma (both sides permuted consistently).
//  MFMA math / windows / tree kernel byte-identical to r11 (verified correct).

#define NTW   (21 * 15 * 16 * 32)
#define TWBYTES (NTW * 2)
#define WFRAG_HALFS (3 * 2 * 64 * 8)     // [g][frag][lane][8] bf16
#define WFRAG_BYTES (WFRAG_HALFS * 2)
#define POOL_HALF 10080
#define POOL_BYTES (POOL_HALF * 2)

typedef __fp16 h2v __attribute__((ext_vector_type(2)));
typedef short short8v __attribute__((ext_vector_type(8)));
typedef float float4v __attribute__((ext_vector_type(4)));
union HU { unsigned u; h2v v; };
union FRAG { uint4 u; short8v s; };

#if defined(__has_builtin)
#if __has_builtin(__builtin_amdgcn_fdot2)
#define HAVE_FDOT2 1
#endif
#endif

__device__ __forceinline__ float sigmoidf_(float v) {
    return 1.0f / (1.0f + __expf(-v));
}
__device__ __forceinline__ h2v as_h2(unsigned x) { HU t; t.u = x; return t.v; }
__device__ __forceinline__ ushort f2bf(float v) {
    unsigned u = __float_as_uint(v);
    u += 0x7fffu + ((u >> 16) & 1u);
    return (ushort)(u >> 16);
}
__device__ __forceinline__ unsigned pack_bf2(float a, float b) {   // {lo=a, hi=b}
    unsigned ua = __float_as_uint(a); ua += 0x7fffu + ((ua >> 16) & 1u);
    unsigned ub = __float_as_uint(b); ub += 0x7fffu + ((ub >> 16) & 1u);
    return (ua >> 16) | (ub & 0xffff0000u);
}

// ---- prep 1: tree weights fp32 -> f16 [gh][f][o][32] in SIGMA layout:
//  e' = parity*16 + half*8 + pxl ; pxl==7 -> 0 ; px = half*7+pxl, w=px>>1, j=px&1
__global__ __launch_bounds__(256) void prep_tw(
    const float* __restrict__ tw, __half* __restrict__ tw2)
{
    int i = blockIdx.x * 256 + threadIdx.x;
    if (i >= NTW) return;
    const int e   = i & 31;
    const int o   = (i >> 5) & 15;
    const int fgh = i >> 9;
    const int f   = fgh % 15, gh = fgh / 15;
    const int g   = gh / 7,  h  = gh % 7;
    const int parity = e >> 4, rem = e & 15, half = rem >> 3, pxl = rem & 7;
    float v = 0.f;
    if (pxl < 7) {
        const int px = half * 7 + pxl;
        const int w = px >> 1, j = px & 1;
        v = tw[o * 8820 + f * 588 + g * 196 + h * 28 + w * 4 + parity * 2 + j];
    }
    tw2[i] = __float2half(v);
}

// ---- prep 2: conv weight MFMA fragments, bf16 [g][frag][lane][8] (r11 verbatim) ----
__global__ __launch_bounds__(256) void prep_wf(
    const float* __restrict__ cw, ushort* __restrict__ wfrag)
{
    int i = blockIdx.x * 256 + threadIdx.x;
    if (i >= 384) return;
    const int g  = i >> 7, rem = i & 127, fr = rem >> 6, l = rem & 63;
    const int f  = l & 15, q = l >> 4;
    ushort o[8];
    #pragma unroll
    for (int j = 0; j < 8; ++j) {
        float v = 0.f;
        if (f < 15 && j < 5) {
            if (fr == 0)           v = cw[(g * 15 + f) * 25 + q * 5 + j];
            else if (q == 0)       v = cw[(g * 15 + f) * 25 + 20 + j];
        }
        o[j] = f2bf(v);
    }
    ushort* d = wfrag + ((g * 2 + fr) * 64 + l) * 8;
    *(uint4*)d = make_uint4(
        (unsigned)o[0] | ((unsigned)o[1] << 16),
        (unsigned)o[2] | ((unsigned)o[3] << 16),
        (unsigned)o[4] | ((unsigned)o[5] << 16),
        (unsigned)o[6] | ((unsigned)o[7] << 16));
}

// ---- kernel A: MFMA conv + pool + sigmoid -> LDS pool -> coalesced flush ----
__global__ __launch_bounds__(256) void conv_pool_mfma(
    const float* __restrict__ x,      // (B,3,32,32)
    const float* __restrict__ cb,     // (45,)
    const ushort* __restrict__ wfrag, // [g][frag][lane][8] bf16
    __half* __restrict__ pool16,      // (B, 10080) f16
    int B)
{
    __shared__ __align__(16) ushort s_R[3 * 32 * 30 * 8];  // 46080 B windows
    __shared__ __align__(16) ushort s_pool[315 * 40];      // 25200 B, stride-40 chunks
    __shared__ float  s_cb[45];
    __shared__ __align__(16) ushort s_zero[8];

    const int b = blockIdx.x;
    if (b >= B) return;
    const int t = threadIdx.x;

    // ---- build sliding windows: thread t<96 owns (g = t/32, row = t%32) ----
    if (t < 96) {
        const int g = t / 32, row = t % 32;
        const float4* xr = (const float4*)(x + (size_t)b * 3072 + t * 32);
        unsigned u[18], s[18];
        #pragma unroll
        for (int k = 0; k < 8; ++k) {
            const float4 v = xr[k];
            u[2 * k]     = pack_bf2(v.x, v.y);
            u[2 * k + 1] = pack_bf2(v.z, v.w);
        }
        u[16] = 0u; u[17] = 0u;
        #pragma unroll
        for (int k = 0; k < 17; ++k) s[k] = (u[k] >> 16) | (u[k + 1] << 16);
        s[17] = 0u;
        ushort* rb = &s_R[((g * 32 + row) * 30) * 8];
        #pragma unroll
        for (int OX = 0; OX < 30; ++OX) {
            uint4 qd;
            if ((OX & 1) == 0) {
                const int hh = OX >> 1;
                qd = make_uint4(u[hh], u[hh + 1], u[hh + 2], u[hh + 3]);
            } else {
                const int hh = (OX - 1) >> 1;
                qd = make_uint4(s[hh], s[hh + 1], s[hh + 2], s[hh + 3]);
            }
            *(uint4*)&rb[OX * 8] = qd;
        }
    }
    if (t < 45) s_cb[t] = cb[t];
    if (t == 96) *(uint4*)&s_zero[0] = make_uint4(0u, 0u, 0u, 0u);

    // per-lane weight fragments (persist in regs)
    const int lane = t & 63, wv = t >> 6;
    const int q = lane >> 4, oxl = lane & 15;
    FRAG w1[3], w2[3];
    {
        const uint4* wf4 = (const uint4*)wfrag;
        #pragma unroll
        for (int g2 = 0; g2 < 3; ++g2) {
            w1[g2].u = wf4[(g2 * 2 + 0) * 64 + lane];
            w2[g2].u = wf4[(g2 * 2 + 1) * 64 + lane];
        }
    }
    __syncthreads();

    const int LC = q * 240 + oxl * 8;          // lane-constant (halfs)
    const float4v z4 = {0.f, 0.f, 0.f, 0.f};

    #pragma unroll 1
    for (int i = 0; i < 21; ++i) {
        const int tp = wv * 21 + i;            // 84 tile-pairs, wave-chunked
        const int g = tp / 28, r = tp - g * 28, py = r >> 1, half = r & 1;
        const int rowbase = ((g * 32 + 2 * py) * 30) * 8;
        const int off1 = rowbase + LC + half * 112;

        FRAG a10, a11, a20, a21;
        a10.u = *(const uint4*)&s_R[off1];          // rows 2py+q
        a11.u = *(const uint4*)&s_R[off1 + 240];    // rows 2py+1+q
        const ushort* p20 = (q == 0)
            ? &s_R[rowbase + 4 * 240 + oxl * 8 + half * 112] : &s_zero[0];
        const ushort* p21 = (q == 0)
            ? &s_R[rowbase + 5 * 240 + oxl * 8 + half * 112] : &s_zero[0];
        a20.u = *(const uint4*)p20;
        a21.u = *(const uint4*)p21;

        float4v acc0 = __builtin_amdgcn_mfma_f32_16x16x32_bf16(a20.s, w2[g].s, z4, 0, 0, 0);
        acc0 = __builtin_amdgcn_mfma_f32_16x16x32_bf16(a10.s, w1[g].s, acc0, 0, 0, 0);
        float4v acc1 = __builtin_amdgcn_mfma_f32_16x16x32_bf16(a21.s, w2[g].s, z4, 0, 0, 0);
        acc1 = __builtin_amdgcn_mfma_f32_16x16x32_bf16(a11.s, w1[g].s, acc1, 0, 0, 0);

        // epilogue: lane (q, f=oxl) -> pooled px = 2q, 2q+1 ; ONE packed LDS u32
        const int f = oxl;
        if (f < 15) {
            const float bias = s_cb[g * 15 + f];
            const float p0 = fmaxf(fmaxf(acc0[0], acc0[1]), fmaxf(acc1[0], acc1[1]));
            const float p1 = fmaxf(fmaxf(acc0[2], acc0[3]), fmaxf(acc1[2], acc1[3]));
            const unsigned lo = __half_as_ushort(__float2half_rn(sigmoidf_(p0 + bias)));
            const unsigned hi = (q < 3)
                ? (unsigned)__half_as_ushort(__float2half_rn(sigmoidf_(p1 + bias))) : 0u;
            const int chunk = (g * 15 + f) * 7 + (py >> 1);
            const int e0 = (py & 1) * 16 + half * 8 + 2 * q;     // even -> 4B aligned
            *(unsigned*)&s_pool[chunk * 40 + e0] = lo | (hi << 16);
        }
    }
    __syncthreads();

    // coalesced flush: 315 chunks x 4 uint4 (LDS stride 40 halfs, global 32)
    uint4* dst4 = (uint4*)(pool16 + (size_t)b * POOL_HALF);
    for (int i = t; i < 1260; i += 256) {
        const int chunk = i >> 2, k = i & 3;
        dst4[i] = *(const uint4*)&s_pool[chunk * 40 + k * 8];
    }
}

// ---- kernel B: tree, 256 thr = 64 images x 4 f-groups, dot2 (r10 verbatim) ----
__global__ __launch_bounds__(256) void tree_kernel(
    const __half* __restrict__ pool16,
    const __half* __restrict__ tw2,
    const float* __restrict__ tb,
    float* __restrict__ out,
    int B, int nblk)
{
    __shared__ float s_red[256 * 17];

    const int cpx = nblk / 8;
    const int sid = (blockIdx.x % 8) * cpx + blockIdx.x / 8;
    const int gh = sid % 21, tile = sid / 21;
    const int g = gh / 7, h = gh % 7;

    const int t  = threadIdx.x;
    const int bl = t & 63, fg = t >> 6;
    const int b  = tile * 64 + bl;
    if (b >= B) return;

    const int f0 = fg * 4;
    const int nf = (fg < 3) ? 4 : 3;

    float acc[16];
    #pragma unroll
    for (int o = 0; o < 16; ++o) acc[o] = 0.f;

    #pragma unroll 1
    for (int fi = 0; fi < nf; ++fi) {
        const int f = f0 + fi;
        const uint4* pc = (const uint4*)(pool16 + (size_t)b * POOL_HALF
                                         + ((g * 15 + f) * 7 + h) * 32);
        const uint4* wc = (const uint4*)(tw2 + (size_t)((gh * 15 + f) * 16) * 32);
        uint4 pu[4];
        #pragma unroll
        for (int k = 0; k < 4; ++k) pu[k] = pc[k];
        #pragma unroll
        for (int o = 0; o < 16; ++o) {
            #pragma unroll
            for (int k = 0; k < 4; ++k) {
                const uint4 wu = wc[o * 4 + k];
#ifdef HAVE_FDOT2
                acc[o] = __builtin_amdgcn_fdot2(as_h2(pu[k].x), as_h2(wu.x), acc[o], false);
                acc[o] = __builtin_amdgcn_fdot2(as_h2(pu[k].y), as_h2(wu.y), acc[o], false);
                acc[o] = __builtin_amdgcn_fdot2(as_h2(pu[k].z), as_h2(wu.z), acc[o], false);
                acc[o] = __builtin_amdgcn_fdot2(as_h2(pu[k].w), as_h2(wu.w), acc[o], false);
#else
                const unsigned pw[4] = {pu[k].x, pu[k].y, pu[k].z, pu[k].w};
                const unsigned ww[4] = {wu.x, wu.y, wu.z, wu.w};
                #pragma unroll
                for (int qq = 0; qq < 4; ++qq) {
                    acc[o] += __half2float(__ushort_as_half((ushort)(pw[qq] & 0xffff)))
                            * __half2float(__ushort_as_half((ushort)(ww[qq] & 0xffff)));
                    acc[o] += __half2float(__ushort_as_half((ushort)(pw[qq] >> 16)))
                            * __half2float(__ushort_as_half((ushort)(ww[qq] >> 16)));
                }
#endif
            }
        }
    }

    #pragma unroll
    for (int o = 0; o < 16; ++o) s_red[t * 17 + o] = acc[o];
    __syncthreads();

    const int og = t >> 6;
    #pragma unroll
    for (int m = 0; m < 4; ++m) {
        const int o = og * 4 + m;
        float a = s_red[(0 * 64 + bl) * 17 + o] + s_red[(1 * 64 + bl) * 17 + o]
                + s_red[(2 * 64 + bl) * 17 + o] + s_red[(3 * 64 + bl) * 17 + o];
        const int idx = o * 21 + gh;
        out[(size_t)b * 336 + idx] = sigmoidf_(a + tb[idx]);
    }
}

// ---- fallback: round-2 fused kernel verbatim (fp32, known-good) ----
__global__ __launch_bounds__(256) void tree_backbone_legacy(
    const float* __restrict__ x, const float* __restrict__ cw,
    const float* __restrict__ cb, const float* __restrict__ tw,
    const float* __restrict__ tb, float* __restrict__ out, int B)
{
    __shared__ float s_x[3 * 32 * 36];
    __shared__ float s_cwl[45 * 25];
    __shared__ float s_cb[45];
    __shared__ float s_pool[45][197];

    const int b = blockIdx.x;
    if (b >= B) return;
    const int t = threadIdx.x;

    const float4* xs = (const float4*)(x + (size_t)b * 3072);
    for (int i = t; i < 768; i += 256) {
        const float4 v = xs[i];
        const int g = i >> 8, rem = i & 255, r = rem >> 3, qq = rem & 7;
        const int p = ((r & 1) << 4) + (r >> 1);
        *(float4*)&s_x[(g * 32 + p) * 36 + qq * 4] = v;
    }
    for (int i = t; i < 1125; i += 256) s_cwl[i] = cw[i];
    if (t < 45) s_cb[t] = cb[t];
    __syncthreads();

    for (int task = t; task < 1260; task += 256) {
        const int h  = (task >= 630) ? 1 : 0;
        const int tt = task - 630 * h;
        const int c  = tt / 14;
        const int py = tt - c * 14;
        const int g  = c / 15;
        float aA[14], aB[14];
        #pragma unroll
        for (int d = 0; d < 14; ++d) { aA[d] = 0.f; aB[d] = 0.f; }
        #pragma unroll
        for (int dr = 0; dr < 6; ++dr) {
            const float* rp = s_x + (g * 32 + ((dr & 1) << 4) + py + (dr >> 1)) * 36 + 12 * h;
            float f[20];
            #pragma unroll
            for (int k = 0; k < 5; ++k)
                *(float4*)&f[4 * k] = *(const float4*)&rp[4 * k];
            if (dr <= 4)
                #pragma unroll
                for (int kx = 0; kx < 5; ++kx) {
                    const float w = s_cwl[c * 25 + dr * 5 + kx];
                    #pragma unroll
                    for (int d = 0; d < 14; ++d) aA[d] += f[d + kx + 2 * h] * w;
                }
            if (dr >= 1)
                #pragma unroll
                for (int kx = 0; kx < 5; ++kx) {
                    const float w = s_cwl[c * 25 + (dr - 1) * 5 + kx];
                    #pragma unroll
                    for (int d = 0; d < 14; ++d) aB[d] += f[d + kx + 2 * h] * w;
                }
        }
        float* dst = &s_pool[c][py * 14 + 7 * h];
        #pragma unroll
        for (int p = 0; p < 7; ++p) {
            float m = fmaxf(fmaxf(aA[2 * p], aA[2 * p + 1]),
                            fmaxf(aB[2 * p], aB[2 * p + 1]));
            dst[p] = sigmoidf_(m + s_cb[c]);
        }
    }
    __syncthreads();

    for (int idx = t; idx < 336; idx += 256) {
        const int o  = idx / 21;
        const int r2 = idx - o * 21;
        const int g  = r2 / 7;
        const int hh = r2 - g * 7;
        const float* wp = tw + o * 8820 + g * 196 + hh * 28;
        float acc = 0.0f;
        #pragma unroll 1
        for (int f = 0; f < 15; ++f) {
            const float4* wf = (const float4*)(wp + f * 588);
            const float* p0 = &s_pool[g * 15 + f][(2 * hh) * 14];
            const float* p1 = p0 + 14;
            #pragma unroll
            for (int w = 0; w < 7; ++w) {
                const float4 qv = wf[w];
                acc += p0[2 * w] * qv.x + p0[2 * w + 1] * qv.y
                     + p1[2 * w] * qv.z + p1[2 * w + 1] * qv.w;
            }
        }
        out[(size_t)b * 336 + idx] = sigmoidf_(acc + tb[idx]);
    }
}

extern "C" void kernel_launch(void* const* d_in, const int* in_sizes, int n_in,
                              void* d_out, int out_size, void* d_ws, size_t ws_size,
                              hipStream_t stream) {
    const float* x  = (const float*)d_in[0];
    const float* cw = (const float*)d_in[1];
    const float* cb = (const float*)d_in[2];
    const float* tw = (const float*)d_in[3];
    const float* tb = (const float*)d_in[4];
    float* out = (float*)d_out;

    const int B = in_sizes[0] / 3072;   // 4096
    const size_t need = (size_t)TWBYTES + (size_t)WFRAG_BYTES + (size_t)B * POOL_BYTES;
    if (ws_size >= need) {
        __half* tw2    = (__half*)d_ws;
        ushort* wfrag  = (ushort*)((char*)d_ws + TWBYTES);
        __half* pool16 = (__half*)((char*)d_ws + TWBYTES + WFRAG_BYTES);
        const int nblk = (B / 64) * 21;
        prep_tw<<<(NTW + 255) / 256, 256, 0, stream>>>(tw, tw2);
        prep_wf<<<2, 256, 0, stream>>>(cw, wfrag);
        conv_pool_mfma<<<B, 256, 0, stream>>>(x, cb, wfrag, pool16, B);
        tree_kernel<<<nblk, 256, 0, stream>>>(pool16, tw2, tb, out, B, nblk);
    } else {
        tree_backbone_legacy<<<B, 256, 0, stream>>>(x, cw, cb, tw, tb, out, B);
    }
}

// Round 13
// 146.141 us; speedup vs baseline: 1.6031x; 1.2164x over previous
//
#include <hip/hip_runtime.h>
#include <hip/hip_fp16.h>
#include <math.h>

// TreeBackbone — round 13. MFMA conv math identical to r12 (verified); the
// kernel is restructured for residency + thread utilization:
//  - per-g window buffer (15.4KB, reused 3x) instead of all-g 46KB -> LDS
//    46KB total -> 3 blocks/CU (was 2).
//  - window build: 480 fine-grained tasks on ALL 256 threads (5 ds_read_b64 +
//    8 packs + 2 ds_write_b128 each; no u[18]/s[18] register arrays -> no
//    spill candidates). x-plane staged via one coalesced float4/thread.
//  - main loop / epilogue / LDS pool+flush / tree / preps = r12 verbatim.

#define NTW   (21 * 15 * 16 * 32)
#define TWBYTES (NTW * 2)
#define WFRAG_HALFS (3 * 2 * 64 * 8)
#define WFRAG_BYTES (WFRAG_HALFS * 2)
#define POOL_HALF 10080
#define POOL_BYTES (POOL_HALF * 2)

typedef __fp16 h2v __attribute__((ext_vector_type(2)));
typedef short short8v __attribute__((ext_vector_type(8)));
typedef float float4v __attribute__((ext_vector_type(4)));
union HU { unsigned u; h2v v; };
union FRAG { uint4 u; short8v s; };

#if defined(__has_builtin)
#if __has_builtin(__builtin_amdgcn_fdot2)
#define HAVE_FDOT2 1
#endif
#endif

__device__ __forceinline__ float sigmoidf_(float v) {
    return 1.0f / (1.0f + __expf(-v));
}
__device__ __forceinline__ h2v as_h2(unsigned x) { HU t; t.u = x; return t.v; }
__device__ __forceinline__ ushort f2bf(float v) {
    unsigned u = __float_as_uint(v);
    u += 0x7fffu + ((u >> 16) & 1u);
    return (ushort)(u >> 16);
}
__device__ __forceinline__ unsigned pack_bf2(float a, float b) {   // {lo=a, hi=b}
    unsigned ua = __float_as_uint(a); ua += 0x7fffu + ((ua >> 16) & 1u);
    unsigned ub = __float_as_uint(b); ub += 0x7fffu + ((ub >> 16) & 1u);
    return (ua >> 16) | (ub & 0xffff0000u);
}

// ---- prep 1: tree weights -> f16 [gh][f][o][32], SIGMA layout (r12 verbatim) ----
__global__ __launch_bounds__(256) void prep_tw(
    const float* __restrict__ tw, __half* __restrict__ tw2)
{
    int i = blockIdx.x * 256 + threadIdx.x;
    if (i >= NTW) return;
    const int e   = i & 31;
    const int o   = (i >> 5) & 15;
    const int fgh = i >> 9;
    const int f   = fgh % 15, gh = fgh / 15;
    const int g   = gh / 7,  h  = gh % 7;
    const int parity = e >> 4, rem = e & 15, half = rem >> 3, pxl = rem & 7;
    float v = 0.f;
    if (pxl < 7) {
        const int px = half * 7 + pxl;
        const int w = px >> 1, j = px & 1;
        v = tw[o * 8820 + f * 588 + g * 196 + h * 28 + w * 4 + parity * 2 + j];
    }
    tw2[i] = __float2half(v);
}

// ---- prep 2: conv weight MFMA fragments (r12 verbatim) ----
__global__ __launch_bounds__(256) void prep_wf(
    const float* __restrict__ cw, ushort* __restrict__ wfrag)
{
    int i = blockIdx.x * 256 + threadIdx.x;
    if (i >= 384) return;
    const int g  = i >> 7, rem = i & 127, fr = rem >> 6, l = rem & 63;
    const int f  = l & 15, q = l >> 4;
    ushort o[8];
    #pragma unroll
    for (int j = 0; j < 8; ++j) {
        float v = 0.f;
        if (f < 15 && j < 5) {
            if (fr == 0)           v = cw[(g * 15 + f) * 25 + q * 5 + j];
            else if (q == 0)       v = cw[(g * 15 + f) * 25 + 20 + j];
        }
        o[j] = f2bf(v);
    }
    ushort* d = wfrag + ((g * 2 + fr) * 64 + l) * 8;
    *(uint4*)d = make_uint4(
        (unsigned)o[0] | ((unsigned)o[1] << 16),
        (unsigned)o[2] | ((unsigned)o[3] << 16),
        (unsigned)o[4] | ((unsigned)o[5] << 16),
        (unsigned)o[6] | ((unsigned)o[7] << 16));
}

// ---- kernel A: MFMA conv (per-g windows) + pool + sigmoid -> LDS -> flush ----
__global__ __launch_bounds__(256) void conv_pool_mfma(
    const float* __restrict__ x,      // (B,3,32,32)
    const float* __restrict__ cb,     // (45,)
    const ushort* __restrict__ wfrag, // [g][frag][lane][8] bf16
    __half* __restrict__ pool16,      // (B, 10080) f16
    int B)
{
    __shared__ __align__(16) float  s_xf[32 * 40];     // 5120 B g-plane, rows padded
    __shared__ __align__(16) ushort s_W[32 * 30 * 8];  // 15360 B windows (one g)
    __shared__ __align__(16) ushort s_pool[315 * 40];  // 25200 B pool chunks
    __shared__ float s_cb[45];
    __shared__ __align__(16) ushort s_zero[8];

    const int b = blockIdx.x;
    if (b >= B) return;
    const int t = threadIdx.x;
    const int lane = t & 63, wv = t >> 6;
    const int q = lane >> 4, oxl = lane & 15;

    if (t < 45) s_cb[t] = cb[t];
    if (t == 45) *(uint4*)&s_zero[0] = make_uint4(0u, 0u, 0u, 0u);

    // per-lane weight fragments (persist in regs)
    FRAG w1[3], w2[3];
    {
        const uint4* wf4 = (const uint4*)wfrag;
        #pragma unroll
        for (int g2 = 0; g2 < 3; ++g2) {
            w1[g2].u = wf4[(g2 * 2 + 0) * 64 + lane];
            w2[g2].u = wf4[(g2 * 2 + 1) * 64 + lane];
        }
    }

    const float4v z4 = {0.f, 0.f, 0.f, 0.f};

    #pragma unroll 1
    for (int g = 0; g < 3; ++g) {
        // ---- stage g-plane: one coalesced float4 per thread + zero pads ----
        {
            const float4* xg4 = (const float4*)(x + (size_t)b * 3072 + g * 1024);
            const float4 v = xg4[t];
            const int row = t >> 3, qq = t & 7;
            *(float4*)&s_xf[row * 40 + qq * 4] = v;
            if (t < 64) {
                const int r2 = t >> 1, k = t & 1;
                *(float4*)&s_xf[r2 * 40 + 32 + k * 4] = make_float4(0.f, 0.f, 0.f, 0.f);
            }
        }
        __syncthreads();

        // ---- build windows: 480 tasks = (row 0..31, m 0..14) -> OX 2m, 2m+1 ----
        #pragma unroll 1
        for (int task = t; task < 480; task += 256) {
            const int row = task / 15, m = task % 15;
            const float* src = &s_xf[row * 40 + 2 * m];
            float f[10];
            #pragma unroll
            for (int k = 0; k < 5; ++k)
                *(float2*)&f[2 * k] = *(const float2*)&src[2 * k];
            const unsigned e0 = pack_bf2(f[0], f[1]), e1 = pack_bf2(f[2], f[3]);
            const unsigned e2 = pack_bf2(f[4], f[5]), e3 = pack_bf2(f[6], f[7]);
            const unsigned o0 = pack_bf2(f[1], f[2]), o1 = pack_bf2(f[3], f[4]);
            const unsigned o2 = pack_bf2(f[5], f[6]), o3 = pack_bf2(f[7], f[8]);
            ushort* wb = &s_W[(row * 30 + 2 * m) * 8];
            *(uint4*)wb       = make_uint4(e0, e1, e2, e3);
            *(uint4*)(wb + 8) = make_uint4(o0, o1, o2, o3);
        }
        __syncthreads();

        // ---- main: 28 tile-pairs; wave wv owns 7 (math identical to r12) ----
        #pragma unroll 1
        for (int i = 0; i < 7; ++i) {
            const int p = wv * 7 + i;
            const int py = p >> 1, half = p & 1;
            const ushort* base = &s_W[(2 * py + q) * 240 + (oxl + 14 * half) * 8];

            FRAG a10, a11, a20, a21;
            a10.u = *(const uint4*)base;
            a11.u = *(const uint4*)(base + 240);
            const ushort* p20 = (q == 0)
                ? &s_W[(2 * py + 4) * 240 + oxl * 8 + half * 112] : &s_zero[0];
            const ushort* p21 = (q == 0)
                ? &s_W[(2 * py + 5) * 240 + oxl * 8 + half * 112] : &s_zero[0];
            a20.u = *(const uint4*)p20;
            a21.u = *(const uint4*)p21;

            float4v acc0 = __builtin_amdgcn_mfma_f32_16x16x32_bf16(a20.s, w2[g].s, z4, 0, 0, 0);
            acc0 = __builtin_amdgcn_mfma_f32_16x16x32_bf16(a10.s, w1[g].s, acc0, 0, 0, 0);
            float4v acc1 = __builtin_amdgcn_mfma_f32_16x16x32_bf16(a21.s, w2[g].s, z4, 0, 0, 0);
            acc1 = __builtin_amdgcn_mfma_f32_16x16x32_bf16(a11.s, w1[g].s, acc1, 0, 0, 0);

            const int f = oxl;
            if (f < 15) {
                const float bias = s_cb[g * 15 + f];
                const float p0 = fmaxf(fmaxf(acc0[0], acc0[1]), fmaxf(acc1[0], acc1[1]));
                const float p1 = fmaxf(fmaxf(acc0[2], acc0[3]), fmaxf(acc1[2], acc1[3]));
                const unsigned lo = __half_as_ushort(__float2half_rn(sigmoidf_(p0 + bias)));
                const unsigned hi = (q < 3)
                    ? (unsigned)__half_as_ushort(__float2half_rn(sigmoidf_(p1 + bias))) : 0u;
                const int chunk = (g * 15 + f) * 7 + (py >> 1);
                const int e0i = (py & 1) * 16 + half * 8 + 2 * q;
                *(unsigned*)&s_pool[chunk * 40 + e0i] = lo | (hi << 16);
            }
        }
        __syncthreads();
    }

    // ---- coalesced flush: 315 chunks x 4 uint4 ----
    uint4* dst4 = (uint4*)(pool16 + (size_t)b * POOL_HALF);
    for (int i = t; i < 1260; i += 256) {
        const int chunk = i >> 2, k = i & 3;
        dst4[i] = *(const uint4*)&s_pool[chunk * 40 + k * 8];
    }
}

// ---- kernel B: tree (r12 verbatim) ----
__global__ __launch_bounds__(256) void tree_kernel(
    const __half* __restrict__ pool16,
    const __half* __restrict__ tw2,
    const float* __restrict__ tb,
    float* __restrict__ out,
    int B, int nblk)
{
    __shared__ float s_red[256 * 17];

    const int cpx = nblk / 8;
    const int sid = (blockIdx.x % 8) * cpx + blockIdx.x / 8;
    const int gh = sid % 21, tile = sid / 21;
    const int g = gh / 7, h = gh % 7;

    const int t  = threadIdx.x;
    const int bl = t & 63, fg = t >> 6;
    const int b  = tile * 64 + bl;
    if (b >= B) return;

    const int f0 = fg * 4;
    const int nf = (fg < 3) ? 4 : 3;

    float acc[16];
    #pragma unroll
    for (int o = 0; o < 16; ++o) acc[o] = 0.f;

    #pragma unroll 1
    for (int fi = 0; fi < nf; ++fi) {
        const int f = f0 + fi;
        const uint4* pc = (const uint4*)(pool16 + (size_t)b * POOL_HALF
                                         + ((g * 15 + f) * 7 + h) * 32);
        const uint4* wc = (const uint4*)(tw2 + (size_t)((gh * 15 + f) * 16) * 32);
        uint4 pu[4];
        #pragma unroll
        for (int k = 0; k < 4; ++k) pu[k] = pc[k];
        #pragma unroll
        for (int o = 0; o < 16; ++o) {
            #pragma unroll
            for (int k = 0; k < 4; ++k) {
                const uint4 wu = wc[o * 4 + k];
#ifdef HAVE_FDOT2
                acc[o] = __builtin_amdgcn_fdot2(as_h2(pu[k].x), as_h2(wu.x), acc[o], false);
                acc[o] = __builtin_amdgcn_fdot2(as_h2(pu[k].y), as_h2(wu.y), acc[o], false);
                acc[o] = __builtin_amdgcn_fdot2(as_h2(pu[k].z), as_h2(wu.z), acc[o], false);
                acc[o] = __builtin_amdgcn_fdot2(as_h2(pu[k].w), as_h2(wu.w), acc[o], false);
#else
                const unsigned pw[4] = {pu[k].x, pu[k].y, pu[k].z, pu[k].w};
                const unsigned ww[4] = {wu.x, wu.y, wu.z, wu.w};
                #pragma unroll
                for (int qq = 0; qq < 4; ++qq) {
                    acc[o] += __half2float(__ushort_as_half((ushort)(pw[qq] & 0xffff)))
                            * __half2float(__ushort_as_half((ushort)(ww[qq] & 0xffff)));
                    acc[o] += __half2float(__ushort_as_half((ushort)(pw[qq] >> 16)))
                            * __half2float(__ushort_as_half((ushort)(ww[qq] >> 16)));
                }
#endif
            }
        }
    }

    #pragma unroll
    for (int o = 0; o < 16; ++o) s_red[t * 17 + o] = acc[o];
    __syncthreads();

    const int og = t >> 6;
    #pragma unroll
    for (int m = 0; m < 4; ++m) {
        const int o = og * 4 + m;
        float a = s_red[(0 * 64 + bl) * 17 + o] + s_red[(1 * 64 + bl) * 17 + o]
                + s_red[(2 * 64 + bl) * 17 + o] + s_red[(3 * 64 + bl) * 17 + o];
        const int idx = o * 21 + gh;
        out[(size_t)b * 336 + idx] = sigmoidf_(a + tb[idx]);
    }
}

// ---- fallback: round-2 fused kernel verbatim (fp32, known-good) ----
__global__ __launch_bounds__(256) void tree_backbone_legacy(
    const float* __restrict__ x, const float* __restrict__ cw,
    const float* __restrict__ cb, const float* __restrict__ tw,
    const float* __restrict__ tb, float* __restrict__ out, int B)
{
    __shared__ float s_x[3 * 32 * 36];
    __shared__ float s_cwl[45 * 25];
    __shared__ float s_cb[45];
    __shared__ float s_pool[45][197];

    const int b = blockIdx.x;
    if (b >= B) return;
    const int t = threadIdx.x;

    const float4* xs = (const float4*)(x + (size_t)b * 3072);
    for (int i = t; i < 768; i += 256) {
        const float4 v = xs[i];
        const int g = i >> 8, rem = i & 255, r = rem >> 3, qq = rem & 7;
        const int p = ((r & 1) << 4) + (r >> 1);
        *(float4*)&s_x[(g * 32 + p) * 36 + qq * 4] = v;
    }
    for (int i = t; i < 1125; i += 256) s_cwl[i] = cw[i];
    if (t < 45) s_cb[t] = cb[t];
    __syncthreads();

    for (int task = t; task < 1260; task += 256) {
        const int h  = (task >= 630) ? 1 : 0;
        const int tt = task - 630 * h;
        const int c  = tt / 14;
        const int py = tt - c * 14;
        const int g  = c / 15;
        float aA[14], aB[14];
        #pragma unroll
        for (int d = 0; d < 14; ++d) { aA[d] = 0.f; aB[d] = 0.f; }
        #pragma unroll
        for (int dr = 0; dr < 6; ++dr) {
            const float* rp = s_x + (g * 32 + ((dr & 1) << 4) + py + (dr >> 1)) * 36 + 12 * h;
            float f[20];
            #pragma unroll
            for (int k = 0; k < 5; ++k)
                *(float4*)&f[4 * k] = *(const float4*)&rp[4 * k];
            if (dr <= 4)
                #pragma unroll
                for (int kx = 0; kx < 5; ++kx) {
                    const float w = s_cwl[c * 25 + dr * 5 + kx];
                    #pragma unroll
                    for (int d = 0; d < 14; ++d) aA[d] += f[d + kx + 2 * h] * w;
                }
            if (dr >= 1)
                #pragma unroll
                for (int kx = 0; kx < 5; ++kx) {
                    const float w = s_cwl[c * 25 + (dr - 1) * 5 + kx];
                    #pragma unroll
                    for (int d = 0; d < 14; ++d) aB[d] += f[d + kx + 2 * h] * w;
                }
        }
        float* dst = &s_pool[c][py * 14 + 7 * h];
        #pragma unroll
        for (int p = 0; p < 7; ++p) {
            float m = fmaxf(fmaxf(aA[2 * p], aA[2 * p + 1]),
                            fmaxf(aB[2 * p], aB[2 * p + 1]));
            dst[p] = sigmoidf_(m + s_cb[c]);
        }
    }
    __syncthreads();

    for (int idx = t; idx < 336; idx += 256) {
        const int o  = idx / 21;
        const int r2 = idx - o * 21;
        const int g  = r2 / 7;
        const int hh = r2 - g * 7;
        const float* wp = tw + o * 8820 + g * 196 + hh * 28;
        float acc = 0.0f;
        #pragma unroll 1
        for (int f = 0; f < 15; ++f) {
            const float4* wf = (const float4*)(wp + f * 588);
            const float* p0 = &s_pool[g * 15 + f][(2 * hh) * 14];
            const float* p1 = p0 + 14;
            #pragma unroll
            for (int w = 0; w < 7; ++w) {
                const float4 qv = wf[w];
                acc += p0[2 * w] * qv.x + p0[2 * w + 1] * qv.y
                     + p1[2 * w] * qv.z + p1[2 * w + 1] * qv.w;
            }
        }
        out[(size_t)b * 336 + idx] = sigmoidf_(acc + tb[idx]);
    }
}

extern "C" void kernel_launch(void* const* d_in, const int* in_sizes, int n_in,
                              void* d_out, int out_size, void* d_ws, size_t ws_size,
                              hipStream_t stream) {
    const float* x  = (const float*)d_in[0];
    const float* cw = (const float*)d_in[1];
    const float* cb = (const float*)d_in[2];
    const float* tw = (const float*)d_in[3];
    const float* tb = (const float*)d_in[4];
    float* out = (float*)d_out;

    const int B = in_sizes[0] / 3072;   // 4096
    const size_t need = (size_t)TWBYTES + (size_t)WFRAG_BYTES + (size_t)B * POOL_BYTES;
    if (ws_size >= need) {
        __half* tw2    = (__half*)d_ws;
        ushort* wfrag  = (ushort*)((char*)d_ws + TWBYTES);
        __half* pool16 = (__half*)((char*)d_ws + TWBYTES + WFRAG_BYTES);
        const int nblk = (B / 64) * 21;
        prep_tw<<<(NTW + 255) / 256, 256, 0, stream>>>(tw, tw2);
        prep_wf<<<2, 256, 0, stream>>>(cw, wfrag);
        conv_pool_mfma<<<B, 256, 0, stream>>>(x, cb, wfrag, pool16, B);
        tree_kernel<<<nblk, 256, 0, stream>>>(pool16, tw2, tb, out, B, nblk);
    } else {
        tree_backbone_legacy<<<B, 256, 0, stream>>>(x, cw, cb, tw, tb, out, B);
    }
}

// Round 14
// 141.481 us; speedup vs baseline: 1.6559x; 1.0329x over previous
//
#include <hip/hip_runtime.h>
#include <hip/hip_fp16.h>
#include <math.h>

// TreeBackbone — round 14 = round 13 with VALU-issue cuts (the measured
// bottleneck: VALUBusy 54%, MfmaUtil 9%):
//  1) window-build bf16 packing via v_cvt_pk_bf16_f32 (1 instr, was ~4-5).
//  2) epilogue f16 pair pack via cvt_pkrtz (1 instr; r10 precedent).
//  3) prep_tw + prep_wf merged into one launch.
//  Structure / MFMA math / LDS pool+flush / tree kernel = r13 verbatim.

#define NTW   (21 * 15 * 16 * 32)
#define TWBYTES (NTW * 2)
#define WFRAG_HALFS (3 * 2 * 64 * 8)
#define WFRAG_BYTES (WFRAG_HALFS * 2)
#define POOL_HALF 10080
#define POOL_BYTES (POOL_HALF * 2)

typedef __fp16 h2v __attribute__((ext_vector_type(2)));
typedef short short8v __attribute__((ext_vector_type(8)));
typedef float float4v __attribute__((ext_vector_type(4)));
union HU { unsigned u; h2v v; };
union FRAG { uint4 u; short8v s; };

#if defined(__has_builtin)
#if __has_builtin(__builtin_amdgcn_fdot2)
#define HAVE_FDOT2 1
#endif
#endif

__device__ __forceinline__ float sigmoidf_(float v) {
    return 1.0f / (1.0f + __expf(-v));
}
__device__ __forceinline__ h2v as_h2(unsigned x) { HU t; t.u = x; return t.v; }
__device__ __forceinline__ ushort f2bf(float v) {
    unsigned u = __float_as_uint(v);
    u += 0x7fffu + ((u >> 16) & 1u);
    return (ushort)(u >> 16);
}
// HW packed f32->bf16 (lo = a, hi = b) — T12-verified on gfx950
__device__ __forceinline__ unsigned cvtpk_bf16(float a, float b) {
    unsigned r;
    asm volatile("v_cvt_pk_bf16_f32 %0, %1, %2" : "=v"(r) : "v"(a), "v"(b));
    return r;
}
__device__ __forceinline__ unsigned pkrtz(float a, float b) {   // f16 pair, RTZ
    HU t; t.v = __builtin_amdgcn_cvt_pkrtz(a, b); return t.u;
}

// ---- merged prep: [0,NTW) tree weights sigma-f16 ; [NTW,NTW+384) conv wfrag ----
__global__ __launch_bounds__(256) void prep_all(
    const float* __restrict__ tw, const float* __restrict__ cw,
    __half* __restrict__ tw2, ushort* __restrict__ wfrag)
{
    int i = blockIdx.x * 256 + threadIdx.x;
    if (i < NTW) {
        const int e   = i & 31;
        const int o   = (i >> 5) & 15;
        const int fgh = i >> 9;
        const int f   = fgh % 15, gh = fgh / 15;
        const int g   = gh / 7,  h  = gh % 7;
        const int parity = e >> 4, rem = e & 15, half = rem >> 3, pxl = rem & 7;
        float v = 0.f;
        if (pxl < 7) {
            const int px = half * 7 + pxl;
            const int w = px >> 1, j = px & 1;
            v = tw[o * 8820 + f * 588 + g * 196 + h * 28 + w * 4 + parity * 2 + j];
        }
        tw2[i] = __float2half(v);
        return;
    }
    const int j5 = i - NTW;
    if (j5 >= 384) return;
    const int g  = j5 >> 7, rem = j5 & 127, fr = rem >> 6, l = rem & 63;
    const int f  = l & 15, q = l >> 4;
    ushort o[8];
    #pragma unroll
    for (int j = 0; j < 8; ++j) {
        float v = 0.f;
        if (f < 15 && j < 5) {
            if (fr == 0)           v = cw[(g * 15 + f) * 25 + q * 5 + j];
            else if (q == 0)       v = cw[(g * 15 + f) * 25 + 20 + j];
        }
        o[j] = f2bf(v);
    }
    ushort* d = wfrag + ((g * 2 + fr) * 64 + l) * 8;
    *(uint4*)d = make_uint4(
        (unsigned)o[0] | ((unsigned)o[1] << 16),
        (unsigned)o[2] | ((unsigned)o[3] << 16),
        (unsigned)o[4] | ((unsigned)o[5] << 16),
        (unsigned)o[6] | ((unsigned)o[7] << 16));
}

// ---- kernel A: MFMA conv (per-g windows) + pool + sigmoid -> LDS -> flush ----
__global__ __launch_bounds__(256) void conv_pool_mfma(
    const float* __restrict__ x,      // (B,3,32,32)
    const float* __restrict__ cb,     // (45,)
    const ushort* __restrict__ wfrag, // [g][frag][lane][8] bf16
    __half* __restrict__ pool16,      // (B, 10080) f16
    int B)
{
    __shared__ __align__(16) float  s_xf[32 * 40];     // 5120 B g-plane
    __shared__ __align__(16) ushort s_W[32 * 30 * 8];  // 15360 B windows (one g)
    __shared__ __align__(16) ushort s_pool[315 * 40];  // 25200 B pool chunks
    __shared__ float s_cb[45];
    __shared__ __align__(16) ushort s_zero[8];

    const int b = blockIdx.x;
    if (b >= B) return;
    const int t = threadIdx.x;
    const int lane = t & 63, wv = t >> 6;
    const int q = lane >> 4, oxl = lane & 15;

    if (t < 45) s_cb[t] = cb[t];
    if (t == 45) *(uint4*)&s_zero[0] = make_uint4(0u, 0u, 0u, 0u);

    FRAG w1[3], w2[3];
    {
        const uint4* wf4 = (const uint4*)wfrag;
        #pragma unroll
        for (int g2 = 0; g2 < 3; ++g2) {
            w1[g2].u = wf4[(g2 * 2 + 0) * 64 + lane];
            w2[g2].u = wf4[(g2 * 2 + 1) * 64 + lane];
        }
    }

    const float4v z4 = {0.f, 0.f, 0.f, 0.f};

    #pragma unroll 1
    for (int g = 0; g < 3; ++g) {
        // ---- stage g-plane: one coalesced float4 per thread + zero pads ----
        {
            const float4* xg4 = (const float4*)(x + (size_t)b * 3072 + g * 1024);
            const float4 v = xg4[t];
            const int row = t >> 3, qq = t & 7;
            *(float4*)&s_xf[row * 40 + qq * 4] = v;
            if (t < 64) {
                const int r2 = t >> 1, k = t & 1;
                *(float4*)&s_xf[r2 * 40 + 32 + k * 4] = make_float4(0.f, 0.f, 0.f, 0.f);
            }
        }
        __syncthreads();

        // ---- build windows: 480 tasks = (row, m) -> OX 2m, 2m+1 ----
        #pragma unroll 1
        for (int task = t; task < 480; task += 256) {
            const int row = task / 15, m = task % 15;
            const float* src = &s_xf[row * 40 + 2 * m];
            float f[10];
            #pragma unroll
            for (int k = 0; k < 5; ++k)
                *(float2*)&f[2 * k] = *(const float2*)&src[2 * k];
            const unsigned e0 = cvtpk_bf16(f[0], f[1]), e1 = cvtpk_bf16(f[2], f[3]);
            const unsigned e2 = cvtpk_bf16(f[4], f[5]), e3 = cvtpk_bf16(f[6], f[7]);
            const unsigned o0 = cvtpk_bf16(f[1], f[2]), o1 = cvtpk_bf16(f[3], f[4]);
            const unsigned o2 = cvtpk_bf16(f[5], f[6]), o3 = cvtpk_bf16(f[7], f[8]);
            ushort* wb = &s_W[(row * 30 + 2 * m) * 8];
            *(uint4*)wb       = make_uint4(e0, e1, e2, e3);
            *(uint4*)(wb + 8) = make_uint4(o0, o1, o2, o3);
        }
        __syncthreads();

        // ---- main: 28 tile-pairs; wave wv owns 7 (math identical to r12/13) ----
        #pragma unroll 1
        for (int i = 0; i < 7; ++i) {
            const int p = wv * 7 + i;
            const int py = p >> 1, half = p & 1;
            const ushort* base = &s_W[(2 * py + q) * 240 + (oxl + 14 * half) * 8];

            FRAG a10, a11, a20, a21;
            a10.u = *(const uint4*)base;
            a11.u = *(const uint4*)(base + 240);
            const ushort* p20 = (q == 0)
                ? &s_W[(2 * py + 4) * 240 + oxl * 8 + half * 112] : &s_zero[0];
            const ushort* p21 = (q == 0)
                ? &s_W[(2 * py + 5) * 240 + oxl * 8 + half * 112] : &s_zero[0];
            a20.u = *(const uint4*)p20;
            a21.u = *(const uint4*)p21;

            float4v acc0 = __builtin_amdgcn_mfma_f32_16x16x32_bf16(a20.s, w2[g].s, z4, 0, 0, 0);
            acc0 = __builtin_amdgcn_mfma_f32_16x16x32_bf16(a10.s, w1[g].s, acc0, 0, 0, 0);
            float4v acc1 = __builtin_amdgcn_mfma_f32_16x16x32_bf16(a21.s, w2[g].s, z4, 0, 0, 0);
            acc1 = __builtin_amdgcn_mfma_f32_16x16x32_bf16(a11.s, w1[g].s, acc1, 0, 0, 0);

            const int f = oxl;
            if (f < 15) {
                const float bias = s_cb[g * 15 + f];
                const float p0 = fmaxf(fmaxf(acc0[0], acc0[1]), fmaxf(acc1[0], acc1[1]));
                const float p1 = fmaxf(fmaxf(acc0[2], acc0[3]), fmaxf(acc1[2], acc1[3]));
                const float s0 = sigmoidf_(p0 + bias);
                const float s1 = (q < 3) ? sigmoidf_(p1 + bias) : 0.f;
                const int chunk = (g * 15 + f) * 7 + (py >> 1);
                const int e0i = (py & 1) * 16 + half * 8 + 2 * q;
                *(unsigned*)&s_pool[chunk * 40 + e0i] = pkrtz(s0, s1);
            }
        }
        __syncthreads();
    }

    // ---- coalesced flush: 315 chunks x 4 uint4 ----
    uint4* dst4 = (uint4*)(pool16 + (size_t)b * POOL_HALF);
    for (int i = t; i < 1260; i += 256) {
        const int chunk = i >> 2, k = i & 3;
        dst4[i] = *(const uint4*)&s_pool[chunk * 40 + k * 8];
    }
}

// ---- kernel B: tree (r12/13 verbatim) ----
__global__ __launch_bounds__(256) void tree_kernel(
    const __half* __restrict__ pool16,
    const __half* __restrict__ tw2,
    const float* __restrict__ tb,
    float* __restrict__ out,
    int B, int nblk)
{
    __shared__ float s_red[256 * 17];

    const int cpx = nblk / 8;
    const int sid = (blockIdx.x % 8) * cpx + blockIdx.x / 8;
    const int gh = sid % 21, tile = sid / 21;
    const int g = gh / 7, h = gh % 7;

    const int t  = threadIdx.x;
    const int bl = t & 63, fg = t >> 6;
    const int b  = tile * 64 + bl;
    if (b >= B) return;

    const int f0 = fg * 4;
    const int nf = (fg < 3) ? 4 : 3;

    float acc[16];
    #pragma unroll
    for (int o = 0; o < 16; ++o) acc[o] = 0.f;

    #pragma unroll 1
    for (int fi = 0; fi < nf; ++fi) {
        const int f = f0 + fi;
        const uint4* pc = (const uint4*)(pool16 + (size_t)b * POOL_HALF
                                         + ((g * 15 + f) * 7 + h) * 32);
        const uint4* wc = (const uint4*)(tw2 + (size_t)((gh * 15 + f) * 16) * 32);
        uint4 pu[4];
        #pragma unroll
        for (int k = 0; k < 4; ++k) pu[k] = pc[k];
        #pragma unroll
        for (int o = 0; o < 16; ++o) {
            #pragma unroll
            for (int k = 0; k < 4; ++k) {
                const uint4 wu = wc[o * 4 + k];
#ifdef HAVE_FDOT2
                acc[o] = __builtin_amdgcn_fdot2(as_h2(pu[k].x), as_h2(wu.x), acc[o], false);
                acc[o] = __builtin_amdgcn_fdot2(as_h2(pu[k].y), as_h2(wu.y), acc[o], false);
                acc[o] = __builtin_amdgcn_fdot2(as_h2(pu[k].z), as_h2(wu.z), acc[o], false);
                acc[o] = __builtin_amdgcn_fdot2(as_h2(pu[k].w), as_h2(wu.w), acc[o], false);
#else
                const unsigned pw[4] = {pu[k].x, pu[k].y, pu[k].z, pu[k].w};
                const unsigned ww[4] = {wu.x, wu.y, wu.z, wu.w};
                #pragma unroll
                for (int qq = 0; qq < 4; ++qq) {
                    acc[o] += __half2float(__ushort_as_half((ushort)(pw[qq] & 0xffff)))
                            * __half2float(__ushort_as_half((ushort)(ww[qq] & 0xffff)));
                    acc[o] += __half2float(__ushort_as_half((ushort)(pw[qq] >> 16)))
                            * __half2float(__ushort_as_half((ushort)(ww[qq] >> 16)));
                }
#endif
            }
        }
    }

    #pragma unroll
    for (int o = 0; o < 16; ++o) s_red[t * 17 + o] = acc[o];
    __syncthreads();

    const int og = t >> 6;
    #pragma unroll
    for (int m = 0; m < 4; ++m) {
        const int o = og * 4 + m;
        float a = s_red[(0 * 64 + bl) * 17 + o] + s_red[(1 * 64 + bl) * 17 + o]
                + s_red[(2 * 64 + bl) * 17 + o] + s_red[(3 * 64 + bl) * 17 + o];
        const int idx = o * 21 + gh;
        out[(size_t)b * 336 + idx] = sigmoidf_(a + tb[idx]);
    }
}

// ---- fallback: round-2 fused kernel verbatim (fp32, known-good) ----
__global__ __launch_bounds__(256) void tree_backbone_legacy(
    const float* __restrict__ x, const float* __restrict__ cw,
    const float* __restrict__ cb, const float* __restrict__ tw,
    const float* __restrict__ tb, float* __restrict__ out, int B)
{
    __shared__ float s_x[3 * 32 * 36];
    __shared__ float s_cwl[45 * 25];
    __shared__ float s_cb[45];
    __shared__ float s_pool[45][197];

    const int b = blockIdx.x;
    if (b >= B) return;
    const int t = threadIdx.x;

    const float4* xs = (const float4*)(x + (size_t)b * 3072);
    for (int i = t; i < 768; i += 256) {
        const float4 v = xs[i];
        const int g = i >> 8, rem = i & 255, r = rem >> 3, qq = rem & 7;
        const int p = ((r & 1) << 4) + (r >> 1);
        *(float4*)&s_x[(g * 32 + p) * 36 + qq * 4] = v;
    }
    for (int i = t; i < 1125; i += 256) s_cwl[i] = cw[i];
    if (t < 45) s_cb[t] = cb[t];
    __syncthreads();

    for (int task = t; task < 1260; task += 256) {
        const int h  = (task >= 630) ? 1 : 0;
        const int tt = task - 630 * h;
        const int c  = tt / 14;
        const int py = tt - c * 14;
        const int g  = c / 15;
        float aA[14], aB[14];
        #pragma unroll
        for (int d = 0; d < 14; ++d) { aA[d] = 0.f; aB[d] = 0.f; }
        #pragma unroll
        for (int dr = 0; dr < 6; ++dr) {
            const float* rp = s_x + (g * 32 + ((dr & 1) << 4) + py + (dr >> 1)) * 36 + 12 * h;
            float f[20];
            #pragma unroll
            for (int k = 0; k < 5; ++k)
                *(float4*)&f[4 * k] = *(const float4*)&rp[4 * k];
            if (dr <= 4)
                #pragma unroll
                for (int kx = 0; kx < 5; ++kx) {
                    const float w = s_cwl[c * 25 + dr * 5 + kx];
                    #pragma unroll
                    for (int d = 0; d < 14; ++d) aA[d] += f[d + kx + 2 * h] * w;
                }
            if (dr >= 1)
                #pragma unroll
                for (int kx = 0; kx < 5; ++kx) {
                    const float w = s_cwl[c * 25 + (dr - 1) * 5 + kx];
                    #pragma unroll
                    for (int d = 0; d < 14; ++d) aB[d] += f[d + kx + 2 * h] * w;
                }
        }
        float* dst = &s_pool[c][py * 14 + 7 * h];
        #pragma unroll
        for (int p = 0; p < 7; ++p) {
            float m = fmaxf(fmaxf(aA[2 * p], aA[2 * p + 1]),
                            fmaxf(aB[2 * p], aB[2 * p + 1]));
            dst[p] = sigmoidf_(m + s_cb[c]);
        }
    }
    __syncthreads();

    for (int idx = t; idx < 336; idx += 256) {
        const int o  = idx / 21;
        const int r2 = idx - o * 21;
        const int g  = r2 / 7;
        const int hh = r2 - g * 7;
        const float* wp = tw + o * 8820 + g * 196 + hh * 28;
        float acc = 0.0f;
        #pragma unroll 1
        for (int f = 0; f < 15; ++f) {
            const float4* wf = (const float4*)(wp + f * 588);
            const float* p0 = &s_pool[g * 15 + f][(2 * hh) * 14];
            const float* p1 = p0 + 14;
            #pragma unroll
            for (int w = 0; w < 7; ++w) {
                const float4 qv = wf[w];
                acc += p0[2 * w] * qv.x + p0[2 * w + 1] * qv.y
                     + p1[2 * w] * qv.z + p1[2 * w + 1] * qv.w;
            }
        }
        out[(size_t)b * 336 + idx] = sigmoidf_(acc + tb[idx]);
    }
}

extern "C" void kernel_launch(void* const* d_in, const int* in_sizes, int n_in,
                              void* d_out, int out_size, void* d_ws, size_t ws_size,
                              hipStream_t stream) {
    const float* x  = (const float*)d_in[0];
    const float* cw = (const float*)d_in[1];
    const float* cb = (const float*)d_in[2];
    const float* tw = (const float*)d_in[3];
    const float* tb = (const float*)d_in[4];
    float* out = (float*)d_out;

    const int B = in_sizes[0] / 3072;   // 4096
    const size_t need = (size_t)TWBYTES + (size_t)WFRAG_BYTES + (size_t)B * POOL_BYTES;
    if (ws_size >= need) {
        __half* tw2    = (__half*)d_ws;
        ushort* wfrag  = (ushort*)((char*)d_ws + TWBYTES);
        __half* pool16 = (__half*)((char*)d_ws + TWBYTES + WFRAG_BYTES);
        const int nblk = (B / 64) * 21;
        prep_all<<<(NTW + 384 + 255) / 256, 256, 0, stream>>>(tw, cw, tw2, wfrag);
        conv_pool_mfma<<<B, 256, 0, stream>>>(x, cb, wfrag, pool16, B);
        tree_kernel<<<nblk, 256, 0, stream>>>(pool16, tw2, tb, out, B, nblk);
    } else {
        tree_backbone_legacy<<<B, 256, 0, stream>>>(x, cw, cb, tw, tb, out, B);
    }
}

// Round 15
// 136.317 us; speedup vs baseline: 1.7186x; 1.0379x over previous
//
#include <hip/hip_runtime.h>
#include <hip/hip_fp16.h>
#include <math.h>

// TreeBackbone — round 15 = round 14 with occupancy/latency fixes (measured:
// occ 29%, 3 serial HBM exposures, LDS 46KB):
//  1) per-g pool flush: s_pool 25.2->8.4KB, LDS 46->29.2KB -> 5 blocks/CU.
//  2) all 3 g-planes prefetched to registers up front (1 HBM exposure).
//  3) pool image stride 20160->20480B (128B multiple; write-amp falsifier).
//  MFMA math / build / epilogue / tree = r14 verbatim.

#define NTW   (21 * 15 * 16 * 32)
#define TWBYTES (NTW * 2)
#define WFRAG_HALFS (3 * 2 * 64 * 8)
#define WFRAG_BYTES (WFRAG_HALFS * 2)
#define POOL_STRIDE 10240                // halfs per image (20480 B, 128B-mult)
#define POOL_BYTES (POOL_STRIDE * 2)

typedef __fp16 h2v __attribute__((ext_vector_type(2)));
typedef short short8v __attribute__((ext_vector_type(8)));
typedef float float4v __attribute__((ext_vector_type(4)));
union HU { unsigned u; h2v v; };
union FRAG { uint4 u; short8v s; };

#if defined(__has_builtin)
#if __has_builtin(__builtin_amdgcn_fdot2)
#define HAVE_FDOT2 1
#endif
#endif

__device__ __forceinline__ float sigmoidf_(float v) {
    return 1.0f / (1.0f + __expf(-v));
}
__device__ __forceinline__ h2v as_h2(unsigned x) { HU t; t.u = x; return t.v; }
__device__ __forceinline__ ushort f2bf(float v) {
    unsigned u = __float_as_uint(v);
    u += 0x7fffu + ((u >> 16) & 1u);
    return (ushort)(u >> 16);
}
__device__ __forceinline__ unsigned cvtpk_bf16(float a, float b) {
    unsigned r;
    asm volatile("v_cvt_pk_bf16_f32 %0, %1, %2" : "=v"(r) : "v"(a), "v"(b));
    return r;
}
__device__ __forceinline__ unsigned pkrtz(float a, float b) {
    HU t; t.v = __builtin_amdgcn_cvt_pkrtz(a, b); return t.u;
}

// ---- merged prep (r14 verbatim) ----
__global__ __launch_bounds__(256) void prep_all(
    const float* __restrict__ tw, const float* __restrict__ cw,
    __half* __restrict__ tw2, ushort* __restrict__ wfrag)
{
    int i = blockIdx.x * 256 + threadIdx.x;
    if (i < NTW) {
        const int e   = i & 31;
        const int o   = (i >> 5) & 15;
        const int fgh = i >> 9;
        const int f   = fgh % 15, gh = fgh / 15;
        const int g   = gh / 7,  h  = gh % 7;
        const int parity = e >> 4, rem = e & 15, half = rem >> 3, pxl = rem & 7;
        float v = 0.f;
        if (pxl < 7) {
            const int px = half * 7 + pxl;
            const int w = px >> 1, j = px & 1;
            v = tw[o * 8820 + f * 588 + g * 196 + h * 28 + w * 4 + parity * 2 + j];
        }
        tw2[i] = __float2half(v);
        return;
    }
    const int j5 = i - NTW;
    if (j5 >= 384) return;
    const int g  = j5 >> 7, rem = j5 & 127, fr = rem >> 6, l = rem & 63;
    const int f  = l & 15, q = l >> 4;
    ushort o[8];
    #pragma unroll
    for (int j = 0; j < 8; ++j) {
        float v = 0.f;
        if (f < 15 && j < 5) {
            if (fr == 0)           v = cw[(g * 15 + f) * 25 + q * 5 + j];
            else if (q == 0)       v = cw[(g * 15 + f) * 25 + 20 + j];
        }
        o[j] = f2bf(v);
    }
    ushort* d = wfrag + ((g * 2 + fr) * 64 + l) * 8;
    *(uint4*)d = make_uint4(
        (unsigned)o[0] | ((unsigned)o[1] << 16),
        (unsigned)o[2] | ((unsigned)o[3] << 16),
        (unsigned)o[4] | ((unsigned)o[5] << 16),
        (unsigned)o[6] | ((unsigned)o[7] << 16));
}

// ---- kernel A: MFMA conv, per-g pool flush, register-prefetched planes ----
__global__ __launch_bounds__(256) void conv_pool_mfma(
    const float* __restrict__ x,
    const float* __restrict__ cb,
    const ushort* __restrict__ wfrag,
    __half* __restrict__ pool16,      // (B, POOL_STRIDE) f16
    int B)
{
    __shared__ __align__(16) float  s_xf[32 * 40];     // 5120 B g-plane
    __shared__ __align__(16) ushort s_W[32 * 30 * 8];  // 15360 B windows (one g)
    __shared__ __align__(16) ushort s_pool[105 * 40];  // 8400 B (one g's chunks)
    __shared__ float s_cb[45];
    __shared__ __align__(16) ushort s_zero[8];

    const int b = blockIdx.x;
    if (b >= B) return;
    const int t = threadIdx.x;
    const int lane = t & 63, wv = t >> 6;
    const int q = lane >> 4, oxl = lane & 15;

    if (t < 45) s_cb[t] = cb[t];
    if (t == 45) *(uint4*)&s_zero[0] = make_uint4(0u, 0u, 0u, 0u);

    // prefetch all 3 g-planes (one HBM latency exposure)
    float4 xpre[3];
    {
        const float4* x4 = (const float4*)(x + (size_t)b * 3072);
        #pragma unroll
        for (int g = 0; g < 3; ++g) xpre[g] = x4[g * 256 + t];
    }
    FRAG w1[3], w2[3];
    {
        const uint4* wf4 = (const uint4*)wfrag;
        #pragma unroll
        for (int g2 = 0; g2 < 3; ++g2) {
            w1[g2].u = wf4[(g2 * 2 + 0) * 64 + lane];
            w2[g2].u = wf4[(g2 * 2 + 1) * 64 + lane];
        }
    }

    const float4v z4 = {0.f, 0.f, 0.f, 0.f};
    const int row_s = t >> 3, q_s = t & 7;               // staging coords

    #pragma unroll 1
    for (int g = 0; g < 3; ++g) {
        // ---- stage g-plane from registers + zero pads ----
        *(float4*)&s_xf[row_s * 40 + q_s * 4] = xpre[g];
        if (t < 64) {
            const int r2 = t >> 1, k = t & 1;
            *(float4*)&s_xf[r2 * 40 + 32 + k * 4] = make_float4(0.f, 0.f, 0.f, 0.f);
        }
        __syncthreads();

        // ---- build windows: 480 tasks = (row, m) -> OX 2m, 2m+1 ----
        #pragma unroll 1
        for (int task = t; task < 480; task += 256) {
            const int row = task / 15, m = task % 15;
            const float* src = &s_xf[row * 40 + 2 * m];
            float f[10];
            #pragma unroll
            for (int k = 0; k < 5; ++k)
                *(float2*)&f[2 * k] = *(const float2*)&src[2 * k];
            const unsigned e0 = cvtpk_bf16(f[0], f[1]), e1 = cvtpk_bf16(f[2], f[3]);
            const unsigned e2 = cvtpk_bf16(f[4], f[5]), e3 = cvtpk_bf16(f[6], f[7]);
            const unsigned o0 = cvtpk_bf16(f[1], f[2]), o1 = cvtpk_bf16(f[3], f[4]);
            const unsigned o2 = cvtpk_bf16(f[5], f[6]), o3 = cvtpk_bf16(f[7], f[8]);
            ushort* wb = &s_W[(row * 30 + 2 * m) * 8];
            *(uint4*)wb       = make_uint4(e0, e1, e2, e3);
            *(uint4*)(wb + 8) = make_uint4(o0, o1, o2, o3);
        }
        __syncthreads();

        // ---- main: 28 tile-pairs; wave wv owns 7 (math = r12/13/14) ----
        #pragma unroll 1
        for (int i = 0; i < 7; ++i) {
            const int p = wv * 7 + i;
            const int py = p >> 1, half = p & 1;
            const ushort* base = &s_W[(2 * py + q) * 240 + (oxl + 14 * half) * 8];

            FRAG a10, a11, a20, a21;
            a10.u = *(const uint4*)base;
            a11.u = *(const uint4*)(base + 240);
            const ushort* p20 = (q == 0)
                ? &s_W[(2 * py + 4) * 240 + oxl * 8 + half * 112] : &s_zero[0];
            const ushort* p21 = (q == 0)
                ? &s_W[(2 * py + 5) * 240 + oxl * 8 + half * 112] : &s_zero[0];
            a20.u = *(const uint4*)p20;
            a21.u = *(const uint4*)p21;

            float4v acc0 = __builtin_amdgcn_mfma_f32_16x16x32_bf16(a20.s, w2[g].s, z4, 0, 0, 0);
            acc0 = __builtin_amdgcn_mfma_f32_16x16x32_bf16(a10.s, w1[g].s, acc0, 0, 0, 0);
            float4v acc1 = __builtin_amdgcn_mfma_f32_16x16x32_bf16(a21.s, w2[g].s, z4, 0, 0, 0);
            acc1 = __builtin_amdgcn_mfma_f32_16x16x32_bf16(a11.s, w1[g].s, acc1, 0, 0, 0);

            const int f = oxl;
            if (f < 15) {
                const float bias = s_cb[g * 15 + f];
                const float p0 = fmaxf(fmaxf(acc0[0], acc0[1]), fmaxf(acc1[0], acc1[1]));
                const float p1 = fmaxf(fmaxf(acc0[2], acc0[3]), fmaxf(acc1[2], acc1[3]));
                const float s0 = sigmoidf_(p0 + bias);
                const float s1 = (q < 3) ? sigmoidf_(p1 + bias) : 0.f;
                const int chunk = f * 7 + (py >> 1);             // local to g
                const int e0i = (py & 1) * 16 + half * 8 + 2 * q;
                *(unsigned*)&s_pool[chunk * 40 + e0i] = pkrtz(s0, s1);
            }
        }
        __syncthreads();

        // ---- per-g flush: 105 chunks x 4 uint4 -> contiguous 6720B ----
        {
            uint4* dst4 = (uint4*)(pool16 + (size_t)b * POOL_STRIDE) + g * 420;
            for (int i = t; i < 420; i += 256) {
                const int chunk = i >> 2, k = i & 3;
                dst4[i] = *(const uint4*)&s_pool[chunk * 40 + k * 8];
            }
        }
        __syncthreads();
    }
}

// ---- kernel B: tree (r14 verbatim, POOL_STRIDE-adjusted) ----
__global__ __launch_bounds__(256) void tree_kernel(
    const __half* __restrict__ pool16,
    const __half* __restrict__ tw2,
    const float* __restrict__ tb,
    float* __restrict__ out,
    int B, int nblk)
{
    __shared__ float s_red[256 * 17];

    const int cpx = nblk / 8;
    const int sid = (blockIdx.x % 8) * cpx + blockIdx.x / 8;
    const int gh = sid % 21, tile = sid / 21;
    const int g = gh / 7, h = gh % 7;

    const int t  = threadIdx.x;
    const int bl = t & 63, fg = t >> 6;
    const int b  = tile * 64 + bl;
    if (b >= B) return;

    const int f0 = fg * 4;
    const int nf = (fg < 3) ? 4 : 3;

    float acc[16];
    #pragma unroll
    for (int o = 0; o < 16; ++o) acc[o] = 0.f;

    #pragma unroll 1
    for (int fi = 0; fi < nf; ++fi) {
        const int f = f0 + fi;
        const uint4* pc = (const uint4*)(pool16 + (size_t)b * POOL_STRIDE
                                         + ((g * 15 + f) * 7 + h) * 32);
        const uint4* wc = (const uint4*)(tw2 + (size_t)((gh * 15 + f) * 16) * 32);
        uint4 pu[4];
        #pragma unroll
        for (int k = 0; k < 4; ++k) pu[k] = pc[k];
        #pragma unroll
        for (int o = 0; o < 16; ++o) {
            #pragma unroll
            for (int k = 0; k < 4; ++k) {
                const uint4 wu = wc[o * 4 + k];
#ifdef HAVE_FDOT2
                acc[o] = __builtin_amdgcn_fdot2(as_h2(pu[k].x), as_h2(wu.x), acc[o], false);
                acc[o] = __builtin_amdgcn_fdot2(as_h2(pu[k].y), as_h2(wu.y), acc[o], false);
                acc[o] = __builtin_amdgcn_fdot2(as_h2(pu[k].z), as_h2(wu.z), acc[o], false);
                acc[o] = __builtin_amdgcn_fdot2(as_h2(pu[k].w), as_h2(wu.w), acc[o], false);
#else
                const unsigned pw[4] = {pu[k].x, pu[k].y, pu[k].z, pu[k].w};
                const unsigned ww[4] = {wu.x, wu.y, wu.z, wu.w};
                #pragma unroll
                for (int qq = 0; qq < 4; ++qq) {
                    acc[o] += __half2float(__ushort_as_half((ushort)(pw[qq] & 0xffff)))
                            * __half2float(__ushort_as_half((ushort)(ww[qq] & 0xffff)));
                    acc[o] += __half2float(__ushort_as_half((ushort)(pw[qq] >> 16)))
                            * __half2float(__ushort_as_half((ushort)(ww[qq] >> 16)));
                }
#endif
            }
        }
    }

    #pragma unroll
    for (int o = 0; o < 16; ++o) s_red[t * 17 + o] = acc[o];
    __syncthreads();

    const int og = t >> 6;
    #pragma unroll
    for (int m = 0; m < 4; ++m) {
        const int o = og * 4 + m;
        float a = s_red[(0 * 64 + bl) * 17 + o] + s_red[(1 * 64 + bl) * 17 + o]
                + s_red[(2 * 64 + bl) * 17 + o] + s_red[(3 * 64 + bl) * 17 + o];
        const int idx = o * 21 + gh;
        out[(size_t)b * 336 + idx] = sigmoidf_(a + tb[idx]);
    }
}

// ---- fallback: round-2 fused kernel verbatim (fp32, known-good) ----
__global__ __launch_bounds__(256) void tree_backbone_legacy(
    const float* __restrict__ x, const float* __restrict__ cw,
    const float* __restrict__ cb, const float* __restrict__ tw,
    const float* __restrict__ tb, float* __restrict__ out, int B)
{
    __shared__ float s_x[3 * 32 * 36];
    __shared__ float s_cwl[45 * 25];
    __shared__ float s_cb[45];
    __shared__ float s_pool[45][197];

    const int b = blockIdx.x;
    if (b >= B) return;
    const int t = threadIdx.x;

    const float4* xs = (const float4*)(x + (size_t)b * 3072);
    for (int i = t; i < 768; i += 256) {
        const float4 v = xs[i];
        const int g = i >> 8, rem = i & 255, r = rem >> 3, qq = rem & 7;
        const int p = ((r & 1) << 4) + (r >> 1);
        *(float4*)&s_x[(g * 32 + p) * 36 + qq * 4] = v;
    }
    for (int i = t; i < 1125; i += 256) s_cwl[i] = cw[i];
    if (t < 45) s_cb[t] = cb[t];
    __syncthreads();

    for (int task = t; task < 1260; task += 256) {
        const int h  = (task >= 630) ? 1 : 0;
        const int tt = task - 630 * h;
        const int c  = tt / 14;
        const int py = tt - c * 14;
        const int g  = c / 15;
        float aA[14], aB[14];
        #pragma unroll
        for (int d = 0; d < 14; ++d) { aA[d] = 0.f; aB[d] = 0.f; }
        #pragma unroll
        for (int dr = 0; dr < 6; ++dr) {
            const float* rp = s_x + (g * 32 + ((dr & 1) << 4) + py + (dr >> 1)) * 36 + 12 * h;
            float f[20];
            #pragma unroll
            for (int k = 0; k < 5; ++k)
                *(float4*)&f[4 * k] = *(const float4*)&rp[4 * k];
            if (dr <= 4)
                #pragma unroll
                for (int kx = 0; kx < 5; ++kx) {
                    const float w = s_cwl[c * 25 + dr * 5 + kx];
                    #pragma unroll
                    for (int d = 0; d < 14; ++d) aA[d] += f[d + kx + 2 * h] * w;
                }
            if (dr >= 1)
                #pragma unroll
                for (int kx = 0; kx < 5; ++kx) {
                    const float w = s_cwl[c * 25 + (dr - 1) * 5 + kx];
                    #pragma unroll
                    for (int d = 0; d < 14; ++d) aB[d] += f[d + kx + 2 * h] * w;
                }
        }
        float* dst = &s_pool[c][py * 14 + 7 * h];
        #pragma unroll
        for (int p = 0; p < 7; ++p) {
            float m = fmaxf(fmaxf(aA[2 * p], aA[2 * p + 1]),
                            fmaxf(aB[2 * p], aB[2 * p + 1]));
            dst[p] = sigmoidf_(m + s_cb[c]);
        }
    }
    __syncthreads();

    for (int idx = t; idx < 336; idx += 256) {
        const int o  = idx / 21;
        const int r2 = idx - o * 21;
        const int g  = r2 / 7;
        const int hh = r2 - g * 7;
        const float* wp = tw + o * 8820 + g * 196 + hh * 28;
        float acc = 0.0f;
        #pragma unroll 1
        for (int f = 0; f < 15; ++f) {
            const float4* wf = (const float4*)(wp + f * 588);
            const float* p0 = &s_pool[g * 15 + f][(2 * hh) * 14];
            const float* p1 = p0 + 14;
            #pragma unroll
            for (int w = 0; w < 7; ++w) {
                const float4 qv = wf[w];
                acc += p0[2 * w] * qv.x + p0[2 * w + 1] * qv.y
                     + p1[2 * w] * qv.z + p1[2 * w + 1] * qv.w;
            }
        }
        out[(size_t)b * 336 + idx] = sigmoidf_(acc + tb[idx]);
    }
}

extern "C" void kernel_launch(void* const* d_in, const int* in_sizes, int n_in,
                              void* d_out, int out_size, void* d_ws, size_t ws_size,
                              hipStream_t stream) {
    const float* x  = (const float*)d_in[0];
    const float* cw = (const float*)d_in[1];
    const float* cb = (const float*)d_in[2];
    const float* tw = (const float*)d_in[3];
    const float* tb = (const float*)d_in[4];
    float* out = (float*)d_out;

    const int B = in_sizes[0] / 3072;   // 4096
    const size_t need = (size_t)TWBYTES + (size_t)WFRAG_BYTES + (size_t)B * POOL_BYTES;
    if (ws_size >= need) {
        __half* tw2    = (__half*)d_ws;
        ushort* wfrag  = (ushort*)((char*)d_ws + TWBYTES);
        __half* pool16 = (__half*)((char*)d_ws + TWBYTES + WFRAG_BYTES);
        const int nblk = (B / 64) * 21;
        prep_all<<<(NTW + 384 + 255) / 256, 256, 0, stream>>>(tw, cw, tw2, wfrag);
        conv_pool_mfma<<<B, 256, 0, stream>>>(x, cb, wfrag, pool16, B);
        tree_kernel<<<nblk, 256, 0, stream>>>(pool16, tw2, tb, out, B, nblk);
    } else {
        tree_backbone_legacy<<<B, 256, 0, stream>>>(x, cw, cb, tw, tb, out, B);
    }
}